// Round 1
// baseline (2354.717 us; speedup 1.0000x reference)
//
#include <hip/hip_runtime.h>
#include <hip/hip_bf16.h>

#define BG 128
#define CGC 64
#define HWPX 4096

__device__ __forceinline__ float sigf(float x){ return 1.0f/(1.0f+__expf(-x)); }
__device__ __forceinline__ unsigned short f2bf(float f){
  __hip_bfloat16 h = __float2bfloat16(f);
  unsigned short u; __builtin_memcpy(&u, &h, sizeof(u)); return u;
}
__device__ __forceinline__ float bf2f(unsigned short u){
  return __uint_as_float(((unsigned)u)<<16);
}

// ---------------- K0: weight transposes + x11 = softmax(gn_b) ----------------
__global__ __launch_bounds__(256) void k_prep(const float* wb1, const float* wb2,
                                              const float* wcat, const float* gnb,
                                              float* w1T, float* w2T, float* wcatT, float* x11){
  int tid = threadIdx.x;
  for (int idx = tid; idx < 64*64*9; idx += 256){
    int co = idx / 576; int rem = idx % 576; int ci = rem / 9; int t = rem % 9;
    w1T[(ci*9+t)*64+co] = wb1[idx];
    w2T[(ci*9+t)*64+co] = wb2[idx];
  }
  for (int idx = tid; idx < 64*128; idx += 256){
    int o = idx >> 7; int i = idx & 127;
    wcatT[i*64+o] = wcat[idx];
  }
  if (tid < 64){
    float g = gnb[tid];
    float m = g;
    for (int s=32; s; s>>=1) m = fmaxf(m, __shfl_xor(m, s));
    float e = __expf(g-m);
    float se = e;
    for (int s=32; s; s>>=1) se += __shfl_xor(se, s);
    x11[tid] = e/se;
  }
}

// ---------------- K1: per-(bg,c) row means + col means -> hwbuf[bg][c][128] ----------------
__global__ __launch_bounds__(256) void k_rowcol(const float* x, float* hwbuf){
  int blk = blockIdx.x;                       // g*64 + c
  const float* px = x + (size_t)blk*HWPX;
  __shared__ float t[64*65];
  int tid = threadIdx.x;
  for (int i = tid; i < 1024; i += 256){
    float4 v = ((const float4*)px)[i];
    int p = i*4; int r = p>>6, c = p&63;
    float* d = &t[r*65+c];
    d[0]=v.x; d[1]=v.y; d[2]=v.z; d[3]=v.w;
  }
  __syncthreads();
  float* out = hwbuf + (size_t)blk*128;
  if (tid < 64){
    float s=0.f;
    #pragma unroll 8
    for (int j=0;j<64;j++) s += t[tid*65+j];
    out[tid] = s*(1.0f/64.0f);
  } else if (tid < 128){
    int j = tid-64; float s=0.f;
    #pragma unroll 8
    for (int i=0;i<64;i++) s += t[i*65+j];
    out[64+j] = s*(1.0f/64.0f);
  }
}

// ---------------- K2: hw = sigmoid(w_hw @ hw + b_hw) -> sigbuf[bg][o][128] ----------------
__global__ __launch_bounds__(256) void k_hwmm(const float* hwbuf, const float* whw,
                                              const float* bhw, float* sigbuf){
  int g = blockIdx.x;
  __shared__ float hl[64*128];
  int tid = threadIdx.x;
  const float* src = hwbuf + (size_t)g*8192;
  for (int i = tid; i < 2048; i += 256) ((float4*)hl)[i] = ((const float4*)src)[i];
  __syncthreads();
  int p  = tid & 127;
  int o0 = (tid >> 7) * 32;
  float acc[32];
  #pragma unroll
  for (int k=0;k<32;k++) acc[k] = bhw[o0+k];
  for (int i=0;i<64;i++){
    float v = hl[i*128+p];
    #pragma unroll
    for (int k=0;k<32;k++) acc[k] = fmaf(whw[(o0+k)*64+i], v, acc[k]);
  }
  float* dst = sigbuf + (size_t)g*8192;
  #pragma unroll
  for (int k=0;k<32;k++) dst[(o0+k)*128+p] = sigf(acc[k]);
}

// ---------------- K3: gate + GroupNorm -> x1 (bf16) ----------------
__global__ __launch_bounds__(256) void k_gate(const float* x, const float* sigbuf,
                                              const float* gnw, const float* gnb,
                                              unsigned short* x1buf){
  int blk = blockIdx.x;                      // g*64 + c
  int g = blk >> 6, c = blk & 63;
  const float* px = x + (size_t)blk*HWPX;
  __shared__ float sg[128];
  __shared__ float rs[4], rs2[4];
  int tid = threadIdx.x;
  if (tid < 128) sg[tid] = sigbuf[(size_t)g*8192 + c*128 + tid];
  __syncthreads();
  float gate[16];
  float s = 0.f, s2 = 0.f;
  #pragma unroll
  for (int k=0;k<4;k++){
    int i = tid + 256*k;
    float4 v = ((const float4*)px)[i];
    int p = i*4; int r = p>>6, col = p&63;
    float sh = sg[r];
    float g0 = v.x*sh*sg[64+col+0];
    float g1 = v.y*sh*sg[64+col+1];
    float g2 = v.z*sh*sg[64+col+2];
    float g3 = v.w*sh*sg[64+col+3];
    gate[4*k+0]=g0; gate[4*k+1]=g1; gate[4*k+2]=g2; gate[4*k+3]=g3;
    s  += g0+g1+g2+g3;
    s2 += g0*g0+g1*g1+g2*g2+g3*g3;
  }
  for (int sh=32; sh; sh>>=1){ s += __shfl_xor(s, sh); s2 += __shfl_xor(s2, sh); }
  int wid = tid >> 6, lane = tid & 63;
  if (lane == 0){ rs[wid]=s; rs2[wid]=s2; }
  __syncthreads();
  float tot  = rs[0]+rs[1]+rs[2]+rs[3];
  float tot2 = rs2[0]+rs2[1]+rs2[2]+rs2[3];
  float mu  = tot*(1.f/4096.f);
  float var = tot2*(1.f/4096.f) - mu*mu;
  float scale = rsqrtf(var + 1e-5f) * gnw[c];
  float shift = gnb[c] - mu*scale;
  unsigned short* dst = x1buf + (size_t)blk*HWPX;
  #pragma unroll
  for (int k=0;k<4;k++){
    int p = 4*(tid + 256*k);
    ushort4 st;
    st.x = f2bf(gate[4*k+0]*scale + shift);
    st.y = f2bf(gate[4*k+1]*scale + shift);
    st.z = f2bf(gate[4*k+2]*scale + shift);
    st.w = f2bf(gate[4*k+3]*scale + shift);
    *(ushort4*)(dst + p) = st;
  }
}

// ---------------- K4: conv3x3 (pad1) + conv3x3 dil2 (pad2) + PReLU + residual -> br (bf16 in d_out) ----------------
#define TW 69
__global__ __launch_bounds__(256) void k_conv(const float* x, const float* w1T, const float* w2T,
                                              const float* bb1, const float* bb2,
                                              const float* a1p, const float* a2p,
                                              unsigned short* brbuf){
  int blk = blockIdx.x;
  int strip = blk & 7;
  int coc   = (blk >> 3) & 7;
  int g     = blk >> 6;
  int co0 = coc*8;
  int r0  = strip*8;
  __shared__ float tile[16*12*TW];
  int tid = threadIdx.x;
  int rl = tid >> 5;              // 0..7
  int c0 = (tid & 31)*2;          // 0..62
  float a1[8][2] = {}; float a2[8][2] = {};
  const float alpha1 = a1p[0], alpha2 = a2p[0];
  const float* xg = x + (size_t)g*CGC*HWPX;

  for (int cc = 0; cc < 4; ++cc){
    int ci0 = cc*16;
    __syncthreads();
    for (int idx = tid; idx < 16*12*68; idx += 256){
      int ci  = idx / 816; int rem = idx % 816;
      int row = rem / 68;  int col = rem % 68 - 2;
      int y = r0 - 2 + row;
      float v = 0.f;
      if ((unsigned)y < 64u && (unsigned)col < 64u)
        v = xg[(size_t)(ci0+ci)*HWPX + y*64 + col];
      tile[(ci*12+row)*TW + col + 2] = v;
    }
    __syncthreads();
    for (int ci = 0; ci < 16; ++ci){
      const float* base = &tile[(ci*12)*TW];
      const float* w1p = w1T + (size_t)(ci0+ci)*9*64 + co0;
      const float* w2p = w2T + (size_t)(ci0+ci)*9*64 + co0;
      #pragma unroll
      for (int dy = 0; dy < 3; ++dy){
        const float* row1 = base + (rl+dy+1)*TW + c0 + 2;
        float v0 = row1[-1], v1 = row1[0], v2 = row1[1], v3 = row1[2];
        #pragma unroll
        for (int dx = 0; dx < 3; ++dx){
          float in0 = (dx==0)?v0:((dx==1)?v1:v2);
          float in1 = (dx==0)?v1:((dx==1)?v2:v3);
          const float* wv = w1p + (dy*3+dx)*64;
          #pragma unroll
          for (int k=0;k<8;k++){
            float w = wv[k];
            a1[k][0] = fmaf(w, in0, a1[k][0]);
            a1[k][1] = fmaf(w, in1, a1[k][1]);
          }
        }
      }
      #pragma unroll
      for (int dy = 0; dy < 3; ++dy){
        const float* row2 = base + (rl+2*dy)*TW + c0 + 2;
        float u0=row2[-2], u1=row2[-1], u2=row2[0], u3=row2[1], u4=row2[2], u5=row2[3];
        #pragma unroll
        for (int dx = 0; dx < 3; ++dx){
          float in0 = (dx==0)?u0:((dx==1)?u2:u4);
          float in1 = (dx==0)?u1:((dx==1)?u3:u5);
          const float* wv = w2p + (dy*3+dx)*64;
          #pragma unroll
          for (int k=0;k<8;k++){
            float w = wv[k];
            a2[k][0] = fmaf(w, in0, a2[k][0]);
            a2[k][1] = fmaf(w, in1, a2[k][1]);
          }
        }
      }
    }
  }
  int r = r0 + rl;
  #pragma unroll
  for (int k=0;k<8;k++){
    float bias1 = bb1[co0+k], bias2 = bb2[co0+k];
    float2 gv = *(const float2*)(xg + (size_t)(co0+k)*HWPX + r*64 + c0);
    float c1a = a1[k][0] + bias1; c1a = (c1a>=0.f? c1a : alpha1*c1a) + gv.x;
    float c1b = a1[k][1] + bias1; c1b = (c1b>=0.f? c1b : alpha1*c1b) + gv.y;
    float c2a = a2[k][0] + bias2; c2a = (c2a>=0.f? c2a : alpha2*c2a) + gv.x;
    float c2b = a2[k][1] + bias2; c2b = (c2b>=0.f? c2b : alpha2*c2b) + gv.y;
    size_t base1 = ((size_t)g*128 + co0 + k)*HWPX + r*64 + c0;
    size_t base2 = ((size_t)g*128 + 64 + co0 + k)*HWPX + r*64 + c0;
    ushort2 s1; s1.x = f2bf(c1a); s1.y = f2bf(c1b);
    ushort2 s2; s2.x = f2bf(c2a); s2.y = f2bf(c2b);
    *(ushort2*)(brbuf + base1) = s1;
    *(ushort2*)(brbuf + base2) = s2;
  }
}

// ---------------- K5: x2 = w_cat @ [br1;br2] + b_cat -> x2 (bf16) ----------------
__global__ __launch_bounds__(256) void k_cat(const unsigned short* brbuf, const float* wcatT,
                                             const float* bcat, unsigned short* x2buf){
  int blk = blockIdx.x;                 // g*16 + strip
  int g = blk >> 4;
  int px = (blk & 15)*256 + threadIdx.x;
  float acc[64] = {};
  const unsigned short* bp = brbuf + (size_t)g*128*HWPX + px;
  for (int i=0;i<128;i++){
    float v = bf2f(bp[(size_t)i*HWPX]);
    const float* w = wcatT + i*64;
    #pragma unroll
    for (int o=0;o<64;o++) acc[o] = fmaf(w[o], v, acc[o]);
  }
  unsigned short* xp = x2buf + (size_t)g*64*HWPX + px;
  #pragma unroll
  for (int o=0;o<64;o++) xp[(size_t)o*HWPX] = f2bf(acc[o] + bcat[o]);
}

// ---------------- K5b: x21 = softmax(mean_hw(x2)) per bg ----------------
__global__ __launch_bounds__(256) void k_x21(const unsigned short* x2buf, float* x21){
  int g = blockIdx.x;
  __shared__ float partial[256];
  int tid = threadIdx.x;
  int o = tid & 63, seg = tid >> 6;
  const unsigned short* base = x2buf + (size_t)g*64*HWPX + (size_t)o*HWPX + seg*1024;
  float s = 0.f;
  for (int m=0;m<256;m++){
    ushort4 u = *(const ushort4*)(base + 4*m);
    s += bf2f(u.x)+bf2f(u.y)+bf2f(u.z)+bf2f(u.w);
  }
  partial[tid] = s;
  __syncthreads();
  if (tid < 64){
    float tot = partial[tid]+partial[tid+64]+partial[tid+128]+partial[tid+192];
    float mean = tot*(1.f/4096.f);
    float mx = mean;
    for (int sh=32; sh; sh>>=1) mx = fmaxf(mx, __shfl_xor(mx, sh));
    float e = __expf(mean-mx);
    float se = e;
    for (int sh=32; sh; sh>>=1) se += __shfl_xor(se, sh);
    x21[g*64+tid] = e/se;
  }
}

// ---------------- K6: weights = x11.x2 + x21.x1 ; out = gx * sigmoid(weights) ----------------
__global__ __launch_bounds__(256) void k_final(const float* x, const unsigned short* x1buf,
                                               const unsigned short* x2buf, const float* x11,
                                               const float* x21, float* out){
  int blk = blockIdx.x;                 // g*4 + strip
  int g = blk >> 2;
  int tid = threadIdx.x;
  int p0 = (blk & 3)*1024 + tid*4;
  __shared__ float wa[64], wb[64];
  if (tid < 64){ wa[tid] = x11[tid]; wb[tid] = x21[g*64+tid]; }
  __syncthreads();
  float w0=0.f,w1=0.f,w2=0.f,w3=0.f;
  const unsigned short* x1p = x1buf + (size_t)g*64*HWPX + p0;
  const unsigned short* x2p = x2buf + (size_t)g*64*HWPX + p0;
  for (int c=0;c<64;c++){
    ushort4 u2 = *(const ushort4*)(x2p + (size_t)c*HWPX);
    ushort4 u1 = *(const ushort4*)(x1p + (size_t)c*HWPX);
    float A = wa[c], Bw = wb[c];
    w0 += A*bf2f(u2.x) + Bw*bf2f(u1.x);
    w1 += A*bf2f(u2.y) + Bw*bf2f(u1.y);
    w2 += A*bf2f(u2.z) + Bw*bf2f(u1.z);
    w3 += A*bf2f(u2.w) + Bw*bf2f(u1.w);
  }
  float s0 = sigf(w0), s1 = sigf(w1), s2 = sigf(w2), s3 = sigf(w3);
  const float* xg = x + (size_t)g*64*HWPX + p0;
  float* op = out + (size_t)g*64*HWPX + p0;
  for (int c=0;c<64;c++){
    float4 v = *(const float4*)(xg + (size_t)c*HWPX);
    float4 r; r.x = v.x*s0; r.y = v.y*s1; r.z = v.z*s2; r.w = v.w*s3;
    *(float4*)(op + (size_t)c*HWPX) = r;
  }
}

extern "C" void kernel_launch(void* const* d_in, const int* in_sizes, int n_in,
                              void* d_out, int out_size, void* d_ws, size_t ws_size,
                              hipStream_t stream) {
  const float* x     = (const float*)d_in[0];
  const float* w_hw  = (const float*)d_in[1];
  const float* b_hw  = (const float*)d_in[2];
  const float* gn_w  = (const float*)d_in[3];
  const float* gn_b  = (const float*)d_in[4];
  const float* w_b1  = (const float*)d_in[5];
  const float* b_b1  = (const float*)d_in[6];
  const float* a_b1  = (const float*)d_in[7];
  const float* w_b2  = (const float*)d_in[8];
  const float* b_b2  = (const float*)d_in[9];
  const float* a_b2  = (const float*)d_in[10];
  const float* w_cat = (const float*)d_in[11];
  const float* b_cat = (const float*)d_in[12];

  char* ws = (char*)d_ws;
  float* w1T   = (float*)(ws + 0);               // 147456 B
  float* w2T   = (float*)(ws + 147456);          // 147456 B
  float* wcatT = (float*)(ws + 294912);          // 32768 B
  float* x11   = (float*)(ws + 327680);          // 256 B
  float* x21   = (float*)(ws + 327936);          // 32768 B
  float* hwbuf = (float*)(ws + 360704);          // 4 MiB
  float* sigb  = (float*)(ws + 4555008);         // 4 MiB
  unsigned short* x1buf = (unsigned short*)(ws + 8749312);    // 64 MiB
  unsigned short* x2buf = (unsigned short*)(ws + 75858176);   // 64 MiB
  unsigned short* brbuf = (unsigned short*)d_out;             // bf16 staging (exactly out_size*4 bytes)
  float* out = (float*)d_out;

  k_prep  <<<1,    256, 0, stream>>>(w_b1, w_b2, w_cat, gn_b, w1T, w2T, wcatT, x11);
  k_rowcol<<<8192, 256, 0, stream>>>(x, hwbuf);
  k_hwmm  <<<128,  256, 0, stream>>>(hwbuf, w_hw, b_hw, sigb);
  k_gate  <<<8192, 256, 0, stream>>>(x, sigb, gn_w, gn_b, x1buf);
  k_conv  <<<8192, 256, 0, stream>>>(x, w1T, w2T, b_b1, b_b2, a_b1, a_b2, brbuf);
  k_cat   <<<2048, 256, 0, stream>>>(brbuf, wcatT, b_cat, x2buf);
  k_x21   <<<128,  256, 0, stream>>>(x2buf, x21);
  k_final <<<512,  256, 0, stream>>>(x, x1buf, x2buf, x11, x21, out);
}

// Round 2
// 341.839 us; speedup vs baseline: 6.8884x; 6.8884x over previous
//
#include <hip/hip_runtime.h>
#include <hip/hip_bf16.h>

#define HWPX 4096

typedef __attribute__((ext_vector_type(8))) short short8v;
typedef __attribute__((ext_vector_type(4))) float f32x4;
#define MFMA(a,b,c) __builtin_amdgcn_mfma_f32_16x16x32_bf16(a,b,c,0,0,0)

__device__ __forceinline__ float sigf(float x){ return 1.0f/(1.0f+__expf(-x)); }
__device__ __forceinline__ unsigned short f2bf(float f){
  __hip_bfloat16 h = __float2bfloat16(f);
  unsigned short u; __builtin_memcpy(&u, &h, sizeof(u)); return u;
}
__device__ __forceinline__ float bf2f(unsigned short u){
  return __uint_as_float(((unsigned)u)<<16);
}

// ---------------- K0: weight images (bf16, LDS-ready, swizzled) + x11 = softmax(gn_b) -------------
// wimg: [q2][conv2][tap9][co64][slot4^swz][e8] bf16  (73728 B per chunk q)
// wcimg: [o64][slot16^swz][e8] bf16 (16384 B)
__global__ __launch_bounds__(256) void k_prep(const float* wb1, const float* wb2,
                                              const float* wcat, const float* gnb,
                                              unsigned short* wimg, unsigned short* wcimg,
                                              float* x11){
  int tid = threadIdx.x;
  for (int idx = tid; idx < 73728; idx += 256){
    int q    = idx / 36864;
    int rem  = idx % 36864;
    int conv = rem / 18432;
    int rem2 = rem % 18432;
    int tap  = rem2 / 2048;
    int rem3 = rem2 % 2048;
    int co   = rem3 / 32;
    int cil  = rem3 % 32;
    int s = cil >> 3, e = cil & 7;
    int ci = q*32 + cil;
    const float* src = conv ? wb2 : wb1;
    float v = src[(co*64 + ci)*9 + tap];
    int dst = ((q*18 + conv*9 + tap)*64 + co)*32 + ((s ^ ((co>>1)&3))*8 + e);
    wimg[dst] = f2bf(v);
  }
  for (int idx = tid; idx < 8192; idx += 256){
    int o = idx >> 7, ch = idx & 127;
    int s = ch >> 3, e = ch & 7;
    float v = wcat[o*128 + ch];
    wcimg[o*128 + ((s ^ (o&7))*8 + e)] = f2bf(v);
  }
  if (tid < 64){
    float g = gnb[tid];
    float m = g;
    for (int s=32; s; s>>=1) m = fmaxf(m, __shfl_xor(m, s));
    float e = __expf(g-m);
    float se = e;
    for (int s=32; s; s>>=1) se += __shfl_xor(se, s);
    x11[tid] = e/se;
  }
}

// ---------------- K1: per-(bg,c) row means + col means -> hwbuf[bg][c][128] ----------------
__global__ __launch_bounds__(256) void k_rowcol(const float* x, float* hwbuf){
  int blk = blockIdx.x;                       // g*64 + c
  const float* px = x + (size_t)blk*HWPX;
  __shared__ float t[64*65];
  int tid = threadIdx.x;
  for (int i = tid; i < 1024; i += 256){
    float4 v = ((const float4*)px)[i];
    int p = i*4; int r = p>>6, c = p&63;
    float* d = &t[r*65+c];
    d[0]=v.x; d[1]=v.y; d[2]=v.z; d[3]=v.w;
  }
  __syncthreads();
  float* out = hwbuf + (size_t)blk*128;
  if (tid < 64){
    float s=0.f;
    #pragma unroll 8
    for (int j=0;j<64;j++) s += t[tid*65+j];
    out[tid] = s*(1.0f/64.0f);
  } else if (tid < 128){
    int j = tid-64; float s=0.f;
    #pragma unroll 8
    for (int i=0;i<64;i++) s += t[i*65+j];
    out[64+j] = s*(1.0f/64.0f);
  }
}

// ---------------- K2: hw = sigmoid(w_hw @ hw + b_hw) -> sigbuf[bg][o][128] ----------------
__global__ __launch_bounds__(256) void k_hwmm(const float* hwbuf, const float* whw,
                                              const float* bhw, float* sigbuf){
  int g = blockIdx.x;
  __shared__ float hl[64*128];
  int tid = threadIdx.x;
  const float* src = hwbuf + (size_t)g*8192;
  for (int i = tid; i < 2048; i += 256) ((float4*)hl)[i] = ((const float4*)src)[i];
  __syncthreads();
  int p  = tid & 127;
  int o0 = (tid >> 7) * 32;
  float acc[32];
  #pragma unroll
  for (int k=0;k<32;k++) acc[k] = bhw[o0+k];
  for (int i=0;i<64;i++){
    float v = hl[i*128+p];
    #pragma unroll
    for (int k=0;k<32;k++) acc[k] = fmaf(whw[(o0+k)*64+i], v, acc[k]);
  }
  float* dst = sigbuf + (size_t)g*8192;
  #pragma unroll
  for (int k=0;k<32;k++) dst[(o0+k)*128+p] = sigf(acc[k]);
}

// ---------------- K3: gate + GroupNorm -> x1 (bf16) ----------------
__global__ __launch_bounds__(256) void k_gate(const float* x, const float* sigbuf,
                                              const float* gnw, const float* gnb,
                                              unsigned short* x1buf){
  int blk = blockIdx.x;                      // g*64 + c
  int g = blk >> 6, c = blk & 63;
  const float* px = x + (size_t)blk*HWPX;
  __shared__ float sg[128];
  __shared__ float rs[4], rs2[4];
  int tid = threadIdx.x;
  if (tid < 128) sg[tid] = sigbuf[(size_t)g*8192 + c*128 + tid];
  __syncthreads();
  float gate[16];
  float s = 0.f, s2 = 0.f;
  #pragma unroll
  for (int k=0;k<4;k++){
    int i = tid + 256*k;
    float4 v = ((const float4*)px)[i];
    int p = i*4; int r = p>>6, col = p&63;
    float sh = sg[r];
    float g0 = v.x*sh*sg[64+col+0];
    float g1 = v.y*sh*sg[64+col+1];
    float g2 = v.z*sh*sg[64+col+2];
    float g3 = v.w*sh*sg[64+col+3];
    gate[4*k+0]=g0; gate[4*k+1]=g1; gate[4*k+2]=g2; gate[4*k+3]=g3;
    s  += g0+g1+g2+g3;
    s2 += g0*g0+g1*g1+g2*g2+g3*g3;
  }
  for (int sh=32; sh; sh>>=1){ s += __shfl_xor(s, sh); s2 += __shfl_xor(s2, sh); }
  int wid = tid >> 6, lane = tid & 63;
  if (lane == 0){ rs[wid]=s; rs2[wid]=s2; }
  __syncthreads();
  float tot  = rs[0]+rs[1]+rs[2]+rs[3];
  float tot2 = rs2[0]+rs2[1]+rs2[2]+rs2[3];
  float mu  = tot*(1.f/4096.f);
  float var = tot2*(1.f/4096.f) - mu*mu;
  float scale = rsqrtf(var + 1e-5f) * gnw[c];
  float shift = gnb[c] - mu*scale;
  unsigned short* dst = x1buf + (size_t)blk*HWPX;
  #pragma unroll
  for (int k=0;k<4;k++){
    int p = 4*(tid + 256*k);
    ushort4 st;
    st.x = f2bf(gate[4*k+0]*scale + shift);
    st.y = f2bf(gate[4*k+1]*scale + shift);
    st.z = f2bf(gate[4*k+2]*scale + shift);
    st.w = f2bf(gate[4*k+3]*scale + shift);
    *(ushort4*)(dst + p) = st;
  }
}

// ---------------- K4: fused MFMA conv3x3(d=1) + conv3x3(d=2) + PReLU + residual + 1x1 cat conv ----
// grid = 128 g * 8 strips ; 512 threads (8 waves: waves 0-3 conv1, 4-7 conv2; c0 = (w&3)*16)
// LDS map: stage phase: [0,73728) weights chunk, [73728,125952) input tile (12r x 4slot x 68c x 8e bf16)
//          epi phase:   [0,131072) br[px512][ch128 swz] bf16, [131072,147456) wcat image (persistent)
__global__ __launch_bounds__(512, 2) void k_convcat(const float* __restrict__ x,
                                                    const char* __restrict__ wimg,
                                                    const char* __restrict__ wcimg,
                                                    const float* __restrict__ bb1,
                                                    const float* __restrict__ bb2,
                                                    const float* __restrict__ a1p,
                                                    const float* __restrict__ a2p,
                                                    const float* __restrict__ bcat,
                                                    unsigned short* __restrict__ x2buf,
                                                    float* __restrict__ x2mean){
  extern __shared__ char smem[];
  char* WLDS  = smem;              // 73728
  char* INLDS = smem + 73728;      // 52224
  char* BR    = smem;              // 131072 (epilogue)
  char* WC    = smem + 131072;     // 16384  (persistent)

  const int tid = threadIdx.x;
  const int g = blockIdx.x >> 3;
  const int strip = blockIdx.x & 7;
  const int r0 = strip * 8;
  const int w = tid >> 6;
  const int lane = tid & 63;
  const int l15 = lane & 15;
  const int lg  = lane >> 4;
  const int conv = w >> 2;
  const int c0 = (w & 3) * 16;
  const int dil = conv + 1;

  // stage wcat image (persistent region)
  {
    const f32x4* src = (const f32x4*)wcimg;
    f32x4* dst = (f32x4*)WC;
    dst[tid*2]   = src[tid*2];
    dst[tid*2+1] = src[tid*2+1];
  }
  // zero input-tile pad columns {0,1,66,67}
  if (tid < 192){
    int row = tid >> 4;
    int rem = tid & 15;
    int slot = rem >> 2;
    int pc = rem & 3;
    int col = (pc < 2) ? pc : (pc + 64);
    f32x4 z = {0.f,0.f,0.f,0.f};
    *(f32x4*)(INLDS + (((row*4 + slot)*68 + col) << 4)) = z;
  }

  f32x4 acc[4][8];
  #pragma unroll
  for (int m=0;m<4;m++)
    #pragma unroll
    for (int r=0;r<8;r++)
      acc[m][r] = (f32x4){0.f,0.f,0.f,0.f};

  const int wlane = l15*64 + ((lg ^ ((l15>>1)&3))<<4);
  const char* wA_base = WLDS + conv*36864 + wlane;
  const int in_lane = lg*1088 + ((c0 + 2 + l15)<<4);
  const char* inb = INLDS + in_lane - 32;   // bias so all offsets >= 0

  for (int q=0; q<2; ++q){
    __syncthreads();
    // ---- stage weights chunk q (linear copy; swizzle pre-baked) ----
    {
      const char* src = wimg + q*73728;
      #pragma unroll
      for (int rd=0; rd<9; ++rd)
        *(f32x4*)(WLDS + tid*16 + rd*8192) = *(const f32x4*)(src + tid*16 + rd*8192);
    }
    // ---- stage input chunk q: f32 -> bf16, [row][slot][col][e] ----
    #pragma unroll
    for (int rd=0; rd<6; ++rd){
      int p = rd*8 + (tid>>6);
      int row = p >> 2, slot = p & 3;
      int col = tid & 63;
      int rg = r0 - 2 + row;
      unsigned pk[4];
      if ((unsigned)rg < 64u){
        const float* src = x + ((size_t)(g*64 + q*32 + slot*8))*HWPX + rg*64 + col;
        float v[8];
        #pragma unroll
        for (int j=0;j<8;j++) v[j] = src[(size_t)j*HWPX];
        #pragma unroll
        for (int wd=0; wd<4; wd++)
          pk[wd] = (unsigned)f2bf(v[2*wd]) | ((unsigned)f2bf(v[2*wd+1])<<16);
      } else {
        pk[0]=pk[1]=pk[2]=pk[3]=0u;
      }
      f32x4 st; __builtin_memcpy(&st, pk, 16);
      *(f32x4*)(INLDS + (((row*4 + slot)*68 + col + 2) << 4)) = st;
    }
    __syncthreads();
    // ---- MFMA over 9 taps ----
    #pragma unroll
    for (int tap=0; tap<9; ++tap){
      const int dy = tap/3 - 1, dx = tap%3 - 1;
      const int off_tap = (dy*dil + 2)*4352 + (dx*dil + 2)*16;
      short8v A0 = *(const short8v*)(wA_base + tap*4096);
      short8v A1 = *(const short8v*)(wA_base + tap*4096 + 1024);
      short8v A2 = *(const short8v*)(wA_base + tap*4096 + 2048);
      short8v A3 = *(const short8v*)(wA_base + tap*4096 + 3072);
      const char* ib = inb + off_tap;
      #pragma unroll
      for (int r=0; r<8; ++r){
        short8v B = *(const short8v*)(ib + r*4352);
        acc[0][r] = MFMA(A0, B, acc[0][r]);
        acc[1][r] = MFMA(A1, B, acc[1][r]);
        acc[2][r] = MFMA(A2, B, acc[2][r]);
        acc[3][r] = MFMA(A3, B, acc[3][r]);
      }
    }
  }

  // ---- epilogue: bias + PReLU + residual(gx, f32 exact) -> br (swizzled LDS) ----
  __syncthreads();
  {
    const float alpha = conv ? a2p[0] : a1p[0];
    const float* bbp = conv ? bb2 : bb1;
    #pragma unroll
    for (int m=0;m<4;m++){
      #pragma unroll
      for (int reg=0;reg<4;reg++){
        int co = m*16 + lg*4 + reg;
        float bias = bbp[co];
        int ch = conv*64 + co;
        const float* resp = x + ((size_t)(g*64 + co))*HWPX + r0*64 + c0 + l15;
        int swz = ((ch>>3) ^ (l15&7))*16 + (ch&7)*2;
        #pragma unroll
        for (int r=0;r<8;r++){
          float v = acc[m][r][reg] + bias;
          v = (v >= 0.f) ? v : alpha*v;
          v += resp[r*64];
          int pxl = r*64 + c0 + l15;
          *(unsigned short*)(BR + pxl*256 + swz) = f2bf(v);
        }
      }
    }
  }
  __syncthreads();

  // ---- cat 1x1 conv: x2[o][px] = sum_ch wcat[o][ch]*br[ch][px] (+bcat at store) ----
  {
    f32x4 c2[4][4];
    #pragma unroll
    for (int m=0;m<4;m++)
      #pragma unroll
      for (int nf=0;nf<4;nf++)
        c2[m][nf] = (f32x4){0.f,0.f,0.f,0.f};

    #pragma unroll
    for (int kc=0;kc<4;kc++){
      short8v A2_[4];
      #pragma unroll
      for (int m=0;m<4;m++)
        A2_[m] = *(const short8v*)(WC + (m*16 + l15)*256 + (((kc*4 + lg) ^ (l15&7))<<4));
      #pragma unroll
      for (int nf=0;nf<4;nf++){
        int pxl = w*64 + nf*16 + l15;
        short8v B2 = *(const short8v*)(BR + pxl*256 + (((kc*4 + lg) ^ (l15&7))<<4));
        c2[0][nf] = MFMA(A2_[0], B2, c2[0][nf]);
        c2[1][nf] = MFMA(A2_[1], B2, c2[1][nf]);
        c2[2][nf] = MFMA(A2_[2], B2, c2[2][nf]);
        c2[3][nf] = MFMA(A2_[3], B2, c2[3][nf]);
      }
    }
    // store x2 (bf16) + accumulate per-channel partial sums for mean
    #pragma unroll
    for (int m=0;m<4;m++){
      #pragma unroll
      for (int reg=0;reg<4;reg++){
        int o = m*16 + lg*4 + reg;
        float bc = bcat[o];
        float s = 0.f;
        unsigned short* xp = x2buf + ((size_t)(g*64 + o))*HWPX + strip*512 + w*64 + l15;
        #pragma unroll
        for (int nf=0;nf<4;nf++){
          float v = c2[m][nf][reg];
          s += v;
          xp[nf*16] = f2bf(v + bc);
        }
        #pragma unroll
        for (int off=1; off<16; off<<=1) s += __shfl_xor(s, off);
        if (l15 == 0) atomicAdd(&x2mean[g*64 + o], s);
      }
    }
  }
}

// ---------------- K5: x21 = softmax(mean(x2)) from accumulated sums ----------------
__global__ __launch_bounds__(64) void k_x21s(const float* x2mean, const float* bcat, float* x21){
  int g = blockIdx.x;
  int o = threadIdx.x;
  float mean = x2mean[g*64 + o] * (1.f/4096.f) + bcat[o];
  float mx = mean;
  for (int s=32; s; s>>=1) mx = fmaxf(mx, __shfl_xor(mx, s));
  float e = __expf(mean - mx);
  float se = e;
  for (int s=32; s; s>>=1) se += __shfl_xor(se, s);
  x21[g*64 + o] = e/se;
}

// ---------------- K6: weights = x11.x2 + x21.x1 ; out = gx * sigmoid(weights) ----------------
__global__ __launch_bounds__(256) void k_final(const float* x, const unsigned short* x1buf,
                                               const unsigned short* x2buf, const float* x11,
                                               const float* x21, float* out){
  int blk = blockIdx.x;                 // g*4 + strip
  int g = blk >> 2;
  int tid = threadIdx.x;
  int p0 = (blk & 3)*1024 + tid*4;
  __shared__ float wa[64], wb[64];
  if (tid < 64){ wa[tid] = x11[tid]; wb[tid] = x21[g*64+tid]; }
  __syncthreads();
  float w0=0.f,w1=0.f,w2=0.f,w3=0.f;
  const unsigned short* x1p = x1buf + (size_t)g*64*HWPX + p0;
  const unsigned short* x2p = x2buf + (size_t)g*64*HWPX + p0;
  for (int c=0;c<64;c++){
    ushort4 u2 = *(const ushort4*)(x2p + (size_t)c*HWPX);
    ushort4 u1 = *(const ushort4*)(x1p + (size_t)c*HWPX);
    float A = wa[c], Bw = wb[c];
    w0 += A*bf2f(u2.x) + Bw*bf2f(u1.x);
    w1 += A*bf2f(u2.y) + Bw*bf2f(u1.y);
    w2 += A*bf2f(u2.z) + Bw*bf2f(u1.z);
    w3 += A*bf2f(u2.w) + Bw*bf2f(u1.w);
  }
  float s0 = sigf(w0), s1 = sigf(w1), s2 = sigf(w2), s3 = sigf(w3);
  const float* xg = x + (size_t)g*64*HWPX + p0;
  float* op = out + (size_t)g*64*HWPX + p0;
  for (int c=0;c<64;c++){
    float4 v = *(const float4*)(xg + (size_t)c*HWPX);
    float4 r; r.x = v.x*s0; r.y = v.y*s1; r.z = v.z*s2; r.w = v.w*s3;
    *(float4*)(op + (size_t)c*HWPX) = r;
  }
}

extern "C" void kernel_launch(void* const* d_in, const int* in_sizes, int n_in,
                              void* d_out, int out_size, void* d_ws, size_t ws_size,
                              hipStream_t stream) {
  const float* x     = (const float*)d_in[0];
  const float* w_hw  = (const float*)d_in[1];
  const float* b_hw  = (const float*)d_in[2];
  const float* gn_w  = (const float*)d_in[3];
  const float* gn_b  = (const float*)d_in[4];
  const float* w_b1  = (const float*)d_in[5];
  const float* b_b1  = (const float*)d_in[6];
  const float* a_b1  = (const float*)d_in[7];
  const float* w_b2  = (const float*)d_in[8];
  const float* b_b2  = (const float*)d_in[9];
  const float* a_b2  = (const float*)d_in[10];
  const float* w_cat = (const float*)d_in[11];
  const float* b_cat = (const float*)d_in[12];

  char* ws = (char*)d_ws;
  unsigned short* wimg  = (unsigned short*)(ws + 0);          // 147456 B
  unsigned short* wcimg = (unsigned short*)(ws + 147456);     // 16384 B
  float* x11    = (float*)(ws + 163840);                      // 256 B
  float* x21    = (float*)(ws + 164096);                      // 32768 B
  float* x2mean = (float*)(ws + 196864);                      // 32768 B
  float* hwbuf  = (float*)(ws + 229632);                      // 4 MiB
  float* sigb   = (float*)(ws + 4423936);                     // 4 MiB
  unsigned short* x1buf = (unsigned short*)(ws + 8618240);    // 64 MiB
  unsigned short* x2buf = (unsigned short*)(ws + 75727104);   // 64 MiB
  float* out = (float*)d_out;

  hipFuncSetAttribute(reinterpret_cast<const void*>(k_convcat),
                      hipFuncAttributeMaxDynamicSharedMemorySize, 147456);

  k_prep  <<<1,    256, 0, stream>>>(w_b1, w_b2, w_cat, gn_b, wimg, wcimg, x11);
  k_rowcol<<<8192, 256, 0, stream>>>(x, hwbuf);
  k_hwmm  <<<128,  256, 0, stream>>>(hwbuf, w_hw, b_hw, sigb);
  k_gate  <<<8192, 256, 0, stream>>>(x, sigb, gn_w, gn_b, x1buf);
  hipMemsetAsync(x2mean, 0, 32768, stream);
  k_convcat<<<1024, 512, 147456, stream>>>(x, (const char*)wimg, (const char*)wcimg,
                                           b_b1, b_b2, a_b1, a_b2, b_cat, x2buf, x2mean);
  k_x21s  <<<128,  64, 0, stream>>>(x2mean, b_cat, x21);
  k_final <<<512,  256, 0, stream>>>(x, x1buf, x2buf, x11, x21, out);
}